// Round 5
// baseline (990.479 us; speedup 1.0000x reference)
//
#include <hip/hip_runtime.h>
#include <hip/hip_bf16.h>
#include <cmath>

// Problem constants
#define L_SEQ  1024
#define BATCH  16
#define NOUT   512          // n
#define DIN    1024         // 2n = layer input dim = GEMM K
#define NBIG   3072         // 6n = GEMM N
#define NLAYERS 4
#define NTOK   (L_SEQ * BATCH)   // 16384 = GEMM M
#define NCHAIN 16384             // B * 2 * n independent scan chains
#define SEG    64                // segments per chain
#define SEGLEN (L_SEQ / SEG)     // 16 steps per segment
#define VEC    8                 // chains per scan thread (consecutive)

typedef __attribute__((ext_vector_type(8))) short bf16x8;
typedef __attribute__((ext_vector_type(8))) unsigned short u16x8;
typedef __attribute__((ext_vector_type(4))) float f32x4;

__device__ __forceinline__ unsigned short f2bf(float f) {
    unsigned x = __float_as_uint(f);
    unsigned r = (x + 0x7fffu + ((x >> 16) & 1u)) >> 16;   // RNE
    return (unsigned short)r;
}
__device__ __forceinline__ float bf2f(unsigned short hv) {
    return __uint_as_float((unsigned)hv << 16);
}
__device__ __forceinline__ float sigmf(float v) {
    return 1.f / (1.f + __expf(-v));
}
__device__ __forceinline__ void async16(const void* g, const void* l) {
    __builtin_amdgcn_global_load_lds(
        (const __attribute__((address_space(1))) unsigned int*)g,
        (__attribute__((address_space(3))) unsigned int*)l, 16, 0, 0);
}

// ---------------- W convert + transpose: W(1024,3072) f32 -> Wt(3072,1024) bf16 ----------------
__global__ __launch_bounds__(256)
void transpose_w(const float* __restrict__ Ws, unsigned short* __restrict__ Wt) {
    __shared__ float tile[32][33];
    int l = blockIdx.z;
    const float* W = Ws + (size_t)l * DIN * NBIG;
    unsigned short* Wo = Wt + (size_t)l * NBIG * DIN;
    int n0 = blockIdx.x * 32, k0 = blockIdx.y * 32;
    int tx = threadIdx.x & 31, ty = threadIdx.x >> 5;
    #pragma unroll
    for (int i = 0; i < 4; i++)
        tile[ty + 8 * i][tx] = W[(size_t)(k0 + ty + 8 * i) * NBIG + n0 + tx];
    __syncthreads();
    #pragma unroll
    for (int i = 0; i < 4; i++)
        Wo[(size_t)(n0 + ty + 8 * i) * DIN + k0 + tx] = f2bf(tile[tx][ty + 8 * i]);
}

// ---------------- embedding gather: write x fp32 + xbf bf16 ----------------
__global__ void embed_kernel(const int* __restrict__ tok,
                             const float* __restrict__ emb,
                             float* __restrict__ x,
                             unsigned short* __restrict__ xbf) {
    int t = blockIdx.x;
    int row = tok[t];
    float4 v = ((const float4*)(emb + (size_t)row * DIN))[threadIdx.x];
    ((float4*)(x + (size_t)t * DIN))[threadIdx.x] = v;
    ushort4 h;
    h.x = f2bf(v.x); h.y = f2bf(v.y); h.z = f2bf(v.z); h.w = f2bf(v.w);
    ((ushort4*)(xbf + (size_t)t * DIN))[threadIdx.x] = h;
}

// ---------------- bf16 MFMA GEMM: u = x @ W ----------------
// 128x128 tile, BK=64, 2x2 waves, 4x4 16x16x32 MFMA per wave, 2 K-steps per tile.
// XOR-swizzled LDS (chunk ^ (row&7)) staged via global_load_lds w16 with the
// inverse source-side permutation; frag ds_read_b128 <=2-way alias = free.
// At the m97-structure plateau (~850 TF); known ceiling for this K-loop shape.
__global__ __launch_bounds__(256)
void gemm_bf16(const unsigned short* __restrict__ Abf,
               const unsigned short* __restrict__ Bt,
               unsigned short* __restrict__ u_xt,
               unsigned short* __restrict__ u_f,
               unsigned short* __restrict__ u_r) {
    __shared__ __align__(16) unsigned short As[128 * 64];
    __shared__ __align__(16) unsigned short Bs[128 * 64];

    const int tid  = threadIdx.x;
    const int lane = tid & 63;
    const int w    = tid >> 6;
    const int wm   = w & 1, wn = w >> 1;
    const int quad = lane >> 4, l16 = lane & 15;

    const int M0 = blockIdx.y * 128;
    const int N0 = blockIdx.x * 128;

    f32x4 acc[4][4];
    #pragma unroll
    for (int i = 0; i < 4; i++)
        #pragma unroll
        for (int j = 0; j < 4; j++)
            acc[i][j] = (f32x4){0.f, 0.f, 0.f, 0.f};

    const int sr = lane >> 3;                 // row within 8-row group
    const int sc = (lane & 7) ^ sr;           // source k-chunk (swizzle inverse)

    for (int k0 = 0; k0 < DIN; k0 += 64) {
        #pragma unroll
        for (int g = 0; g < 4; g++) {
            int rbase = w * 32 + g * 8;       // wave-uniform 8-row group
            int r = rbase + sr;
            async16(Abf + (size_t)(M0 + r) * DIN + k0 + sc * 8, &As[rbase * 64]);
            async16(Bt  + (size_t)(N0 + r) * DIN + k0 + sc * 8, &Bs[rbase * 64]);
        }
        __syncthreads();

        #pragma unroll
        for (int s = 0; s < 2; s++) {
            bf16x8 af[4], bg[4];
            #pragma unroll
            for (int t = 0; t < 4; t++) {
                int ra = wm * 64 + t * 16 + l16;
                int sa = (s * 4 + quad) ^ (ra & 7);
                af[t] = *(const bf16x8*)&As[ra * 64 + sa * 8];
                int rb = wn * 64 + t * 16 + l16;
                int sb = (s * 4 + quad) ^ (rb & 7);
                bg[t] = *(const bf16x8*)&Bs[rb * 64 + sb * 8];
            }
            #pragma unroll
            for (int i = 0; i < 4; i++)
                #pragma unroll
                for (int j = 0; j < 4; j++)
                    acc[i][j] = __builtin_amdgcn_mfma_f32_16x16x32_bf16(af[i], bg[j], acc[i][j], 0, 0, 0);
        }
        __syncthreads();
    }

    #pragma unroll
    for (int i = 0; i < 4; i++) {
        int gm = M0 + wm * 64 + i * 16 + quad * 4;
        #pragma unroll
        for (int j = 0; j < 4; j++) {
            int gn = N0 + wn * 64 + j * 16 + l16;
            int dir  = gn >= 3 * NOUT;
            int jj   = gn - dir * 3 * NOUT;
            int plane = jj >> 9;          // 0:xt 1:f 2:r (uniform per 16-tile)
            int feat  = jj & 511;
            unsigned short* p = (plane == 0 ? u_xt : plane == 1 ? u_f : u_r)
                                + (size_t)gm * DIN + dir * NOUT + feat;
            #pragma unroll
            for (int r = 0; r < 4; r++) p[(size_t)r * DIN] = f2bf(acc[i][j][r]);
        }
    }
}

// ---------------- chunked SRU scan, 8 chains/thread ----------------
// chain = b*1024 + d*512 + i; element at time t: t*16384 + chain (int-safe, <2^25).
// Thread handles chains [cb, cb+8) (same dir). Segment s: j=0..15 at t = t0 + sgn*j;
//   d=0: t0 = s*16, sgn=+1;  d=1: t0 = 1023 - s*16, sgn=-1.

// Phase A: per (chain, seg): A = prod f, B = segment scan from c=0.
__global__ __launch_bounds__(256)
void scan_phaseA(const unsigned short* __restrict__ u_xt, const unsigned short* __restrict__ u_f,
                 const float* __restrict__ bias,
                 float* __restrict__ Aseg, float* __restrict__ Bseg) {
    int g = blockIdx.x * 256 + threadIdx.x;     // 0 .. 131071
    int grp = g & (NCHAIN / VEC - 1);           // chain-group 0..2047
    int s = g >> 11;                            // segment 0..63
    int cb = grp * VEC;
    int rest = cb & 1023;
    int d = rest >> 9;

    float4 b0 = *(const float4*)(bias + rest);
    float4 b1 = *(const float4*)(bias + rest + 4);
    float bfv[8] = {b0.x, b0.y, b0.z, b0.w, b1.x, b1.y, b1.z, b1.w};

    int t0 = d ? (L_SEQ - 1 - s * SEGLEN) : (s * SEGLEN);
    int idx = t0 * NCHAIN + cb;
    int step = d ? -NCHAIN : NCHAIN;

    float c[8], A[8];
    #pragma unroll
    for (int k = 0; k < 8; k++) { c[k] = 0.f; A[k] = 1.f; }

    #pragma unroll 4
    for (int j = 0; j < SEGLEN; j++) {
        u16x8 xt8 = *(const u16x8*)(u_xt + idx);
        u16x8 f8  = *(const u16x8*)(u_f + idx);
        #pragma unroll
        for (int k = 0; k < 8; k++) {
            float f = sigmf(bf2f(f8[k]) + bfv[k]);
            c[k] = f * c[k] + (1.f - f) * bf2f(xt8[k]);
            A[k] *= f;
        }
        idx += step;
    }
    int og = s * NCHAIN + cb;
    *(float4*)(Aseg + og)     = make_float4(A[0], A[1], A[2], A[3]);
    *(float4*)(Aseg + og + 4) = make_float4(A[4], A[5], A[6], A[7]);
    *(float4*)(Bseg + og)     = make_float4(c[0], c[1], c[2], c[3]);
    *(float4*)(Bseg + og + 4) = make_float4(c[4], c[5], c[6], c[7]);
}

// Phase B: compose 64 segment carries per chain; cstart per segment; final c = hidden.
__global__ __launch_bounds__(256)
void scan_phaseB(const float* __restrict__ Aseg, const float* __restrict__ Bseg,
                 float* __restrict__ cstart, float* __restrict__ c_out) {
    int chain = blockIdx.x * 256 + threadIdx.x;
    float c = 0.f;
    #pragma unroll 8
    for (int s = 0; s < SEG; s++) {
        int g = s * NCHAIN + chain;
        cstart[g] = c;
        c = Aseg[g] * c + Bseg[g];
    }
    c_out[chain] = c;
}

// Phase C: re-scan each segment from true cstart; h in-place on x + bf16 copy.
__global__ __launch_bounds__(256)
void scan_phaseC(const unsigned short* __restrict__ u_xt, const unsigned short* __restrict__ u_f,
                 const unsigned short* __restrict__ u_r,
                 float* __restrict__ x, unsigned short* __restrict__ xbf,
                 const float* __restrict__ bias, const float* __restrict__ cstart,
                 int write_bf) {
    int g = blockIdx.x * 256 + threadIdx.x;
    int grp = g & (NCHAIN / VEC - 1);
    int s = g >> 11;
    int cb = grp * VEC;
    int rest = cb & 1023;
    int d = rest >> 9;

    float4 b0 = *(const float4*)(bias + rest);
    float4 b1 = *(const float4*)(bias + rest + 4);
    float bfv[8] = {b0.x, b0.y, b0.z, b0.w, b1.x, b1.y, b1.z, b1.w};
    float4 r0 = *(const float4*)(bias + 1024 + rest);
    float4 r1 = *(const float4*)(bias + 1024 + rest + 4);
    float brv[8] = {r0.x, r0.y, r0.z, r0.w, r1.x, r1.y, r1.z, r1.w};

    int t0 = d ? (L_SEQ - 1 - s * SEGLEN) : (s * SEGLEN);
    int idx = t0 * NCHAIN + cb;
    int step = d ? -NCHAIN : NCHAIN;

    int og = s * NCHAIN + cb;
    float4 c0 = *(const float4*)(cstart + og);
    float4 c1 = *(const float4*)(cstart + og + 4);
    float c[8] = {c0.x, c0.y, c0.z, c0.w, c1.x, c1.y, c1.z, c1.w};

    #pragma unroll 2
    for (int j = 0; j < SEGLEN; j++) {
        u16x8 xt8 = *(const u16x8*)(u_xt + idx);
        u16x8 f8  = *(const u16x8*)(u_f + idx);
        u16x8 rr8 = *(const u16x8*)(u_r + idx);
        float4 xp0 = *(const float4*)(x + idx);
        float4 xp1 = *(const float4*)(x + idx + 4);
        float xp[8] = {xp0.x, xp0.y, xp0.z, xp0.w, xp1.x, xp1.y, xp1.z, xp1.w};
        float h[8];
        #pragma unroll
        for (int k = 0; k < 8; k++) {
            float f = sigmf(bf2f(f8[k]) + bfv[k]);
            float r = sigmf(bf2f(rr8[k]) + brv[k]);
            c[k] = f * c[k] + (1.f - f) * bf2f(xt8[k]);
            float th = 1.f - 2.f / (__expf(2.f * c[k]) + 1.f);
            h[k] = r * th + (1.f - r) * xp[k];
        }
        *(float4*)(x + idx)     = make_float4(h[0], h[1], h[2], h[3]);
        *(float4*)(x + idx + 4) = make_float4(h[4], h[5], h[6], h[7]);
        if (write_bf) {
            u16x8 hb;
            #pragma unroll
            for (int k = 0; k < 8; k++) hb[k] = f2bf(h[k]);
            *(u16x8*)(xbf + idx) = hb;
        }
        idx += step;
    }
}

// ---------------- launch ----------------
// d_out: [ x (L*B*1024) | hidden (4*B*1024) ] f32.
// Workspace (164 MB): u_xt 32 | u_f 32 | u_r 32 | xbf 32 | Wt 24 | Aseg 4 | Bseg 4 | cstart 4.
extern "C" void kernel_launch(void* const* d_in, const int* in_sizes, int n_in,
                              void* d_out, int out_size, void* d_ws, size_t ws_size,
                              hipStream_t stream) {
    const int*   tok = (const int*)d_in[0];
    const float* emb = (const float*)d_in[2];
    const float* Ws  = (const float*)d_in[3];
    const float* bs  = (const float*)d_in[4];

    float* out    = (float*)d_out;
    float* x      = out;
    float* hidden = out + (size_t)NTOK * DIN;

    char* ws = (char*)d_ws;
    unsigned short* u_xt   = (unsigned short*)ws;                       // 32 MB
    unsigned short* u_f    = (unsigned short*)(ws + (32u  << 20));      // 32 MB
    unsigned short* u_r    = (unsigned short*)(ws + (64u  << 20));      // 32 MB
    unsigned short* xbf    = (unsigned short*)(ws + (96u  << 20));      // 32 MB
    unsigned short* Wt     = (unsigned short*)(ws + (128u << 20));      // 24 MB
    float*          Aseg   = (float*)(ws + (152u << 20));               // 4 MB
    float*          Bseg   = (float*)(ws + (156u << 20));               // 4 MB
    float*          cstart = (float*)(ws + (160u << 20));               // 4 MB

    transpose_w<<<dim3(NBIG / 32, DIN / 32, NLAYERS), 256, 0, stream>>>(Ws, Wt);
    embed_kernel<<<NTOK, 256, 0, stream>>>(tok, emb, x, xbf);

    const int scan_blocks = NCHAIN / VEC * SEG / 256;   // 512

    for (int l = 0; l < NLAYERS; l++) {
        const unsigned short* Wl = Wt + (size_t)l * NBIG * DIN;
        const float* b = bs + (size_t)l * 4 * NOUT;
        gemm_bf16<<<dim3(NBIG / 128, NTOK / 128), 256, 0, stream>>>(xbf, Wl, u_xt, u_f, u_r);
        scan_phaseA<<<scan_blocks, 256, 0, stream>>>(u_xt, u_f, b, Aseg, Bseg);
        scan_phaseB<<<NCHAIN / 256, 256, 0, stream>>>(Aseg, Bseg, cstart,
                                                      hidden + (size_t)l * BATCH * DIN);
        scan_phaseC<<<scan_blocks, 256, 0, stream>>>(u_xt, u_f, u_r, x, xbf, b, cstart,
                                                     l < NLAYERS - 1);
    }
}